// Round 3
// baseline (1069.219 us; speedup 1.0000x reference)
//
#include <hip/hip_runtime.h>

// ---------------------------------------------------------------------------
// GRU_13030930776564: bidirectional GRU, B=64, L=1024, DI=D=DO=256 (fp32 io).
//   P1: X  = bf16( inputs @ Wi + Wi_b )                        [65536 x 256]
//   P2: one merged kernel (grid 1536, matrix = bid>>9), A staged via
//       global_load_lds (16B) with XOR-swizzled source so linear LDS gives
//       conflict-free ds_read_b128:  phys = logical ^ (((logical>>9)&7)<<4.
//       XX = bf16( X @ Wx + Wx_b )
//       XR = bf16( X @ Ux + Ux_b + Wr_b )   (fold recurrent bias)
//       XU = bf16( X @ Rx + Rx_b + Wu_b )
//   R : 64 WGs x 512 thr; WG = 2 sequences (batch x dir). Weights-in-VGPR
//       MFMA, A = h (seq on M-row parity), B = W cols. Lane holds both seqs
//       of its own column in acc regs 0/1 (no LDS transpose).
//       W-frags K-ROTATED per wave (slot i = chunk (wave+i)&7): slot 0 = the
//       wave's OWN columns. R3: slot-0 A-frag is built IN-REGISTER from the
//       just-computed h16 via 1 shfl_xor pack + 4 ds_bpermute (static lane
//       addrs, NO dependence on the hbuf ds_write), and the 4 slot-0 MFMAs
//       issue PRE-barrier into zeroed carried accumulators -> they drain
//       during the barrier window; post-barrier loop covers slots 1..7 only.
//       hbuf stride 288 (parities in disjoint bank-groups, 0 conflicts).
//       Per-step sync: s_barrier + lgkmcnt(0) only (no vmcnt drain).
//   F : out = fp32( (Hf + Hb) @ Wo + Wo_b )
// ws layout (u16 elements, E = 64*1024*256): XX | XR | XU | Hf(=X) | Hb
// ---------------------------------------------------------------------------

typedef float   f32x4 __attribute__((ext_vector_type(4)));
typedef short   s16x8 __attribute__((ext_vector_type(8)));
typedef unsigned int u32;
typedef u32     u32x4 __attribute__((ext_vector_type(4)));
typedef unsigned short u16;

#define LDP  264   // padded row stride for gemm256 At (u16 elems)
#define LDPH 288   // hbuf row stride: 288*2B = 576B = granule 36 ≡ 4 (mod 8)

__device__ __forceinline__ u16 f2bf(float x) {
    u32 u = __float_as_uint(x);
    return (u16)((u + 0x7FFFu + ((u >> 16) & 1u)) >> 16);   // RNE, inputs never NaN
}
__device__ __forceinline__ float bflo(u32 u) { return __uint_as_float(u << 16); }
__device__ __forceinline__ float bfhi(u32 u) { return __uint_as_float(u & 0xFFFF0000u); }
__device__ __forceinline__ float bf2f(u16 v) { return __uint_as_float((u32)v << 16); }

__device__ __forceinline__ float sigm(float z) {
    float e = __builtin_amdgcn_exp2f(z * -1.44269504f);
    return __builtin_amdgcn_rcpf(1.0f + e);
}
__device__ __forceinline__ float tanhfast(float y) {
    float e = __builtin_amdgcn_exp2f(y * 2.88539008f);     // e^(2y)
    return 1.0f - 2.0f * __builtin_amdgcn_rcpf(1.0f + e);  // handles +/-inf saturation
}

// Raw barrier helpers: compiler-level fences sandwich the hw barrier so LDS
// ops can't migrate across it, but NO vmcnt drain is forced.
__device__ __forceinline__ void bar_lgkm() {
    asm volatile("s_waitcnt lgkmcnt(0)" ::: "memory");
    __builtin_amdgcn_s_barrier();
    asm volatile("" ::: "memory");
}
__device__ __forceinline__ void bar_only() {
    asm volatile("" ::: "memory");
    __builtin_amdgcn_s_barrier();
    asm volatile("" ::: "memory");
}

#define GLD_LDS16(g, l) __builtin_amdgcn_global_load_lds( \
    (const __attribute__((address_space(1))) unsigned int*)(g), \
    (__attribute__((address_space(3))) unsigned int*)(l), 16, 0, 0)

// ---------------------------------------------------------------------------
// Generic K=256, N=256 GEMM (P1: f32 A in; F: bf16 A + A2 sum, f32 out).
// ---------------------------------------------------------------------------
__global__ __launch_bounds__(256, 2)
void gemm256(const void* __restrict__ Asrc, int a_f32, const u16* __restrict__ A2,
             const float* __restrict__ W, const float* __restrict__ b1,
             const float* __restrict__ b2, void* __restrict__ Cdst, int c_f32, int M)
{
    __shared__ u16 At[32 * LDP];
    const int tid  = threadIdx.x;
    const int lane = tid & 63, wv = tid >> 6;
    const int quad = lane >> 4, n16 = lane & 15;

    // preload B fragments: bw[nt][kt] holds W[k = kt*32+quad*8+j][col], col = wv*64+nt*16+n16
    s16x8 bw[4][8];
    #pragma unroll
    for (int nt = 0; nt < 4; ++nt) {
        const int col = wv * 64 + nt * 16 + n16;
        #pragma unroll
        for (int kt = 0; kt < 8; ++kt) {
            const int kb0 = kt * 32 + quad * 8;
            s16x8 f;
            #pragma unroll
            for (int j = 0; j < 8; ++j) f[j] = (short)f2bf(W[(kb0 + j) * 256 + col]);
            bw[nt][kt] = f;
        }
    }

    const int arow = tid >> 3, kb = (tid & 7) * 32;  // staging: 32 elements per thread
    float av[32];
    const int nstrip = M >> 5;

    for (int s = (int)blockIdx.x; s < nstrip; s += (int)gridDim.x) {
        // ---- load A strip (32 rows x 256) into regs ----
        const long base = (long)(s * 32 + arow) * 256 + kb;
        if (a_f32) {
            const float4* p = (const float4*)((const float*)Asrc + base);
            #pragma unroll
            for (int i = 0; i < 8; ++i) {
                float4 v = p[i];
                av[i*4+0] = v.x; av[i*4+1] = v.y; av[i*4+2] = v.z; av[i*4+3] = v.w;
            }
        } else {
            const uint4* p = (const uint4*)((const u16*)Asrc + base);
            #pragma unroll
            for (int i = 0; i < 4; ++i) {
                uint4 v = p[i];
                av[i*8+0] = bflo(v.x); av[i*8+1] = bfhi(v.x);
                av[i*8+2] = bflo(v.y); av[i*8+3] = bfhi(v.y);
                av[i*8+4] = bflo(v.z); av[i*8+5] = bfhi(v.z);
                av[i*8+6] = bflo(v.w); av[i*8+7] = bfhi(v.w);
            }
            if (A2) {
                const uint4* q = (const uint4*)(A2 + base);
                #pragma unroll
                for (int i = 0; i < 4; ++i) {
                    uint4 v = q[i];
                    av[i*8+0] += bflo(v.x); av[i*8+1] += bfhi(v.x);
                    av[i*8+2] += bflo(v.y); av[i*8+3] += bfhi(v.y);
                    av[i*8+4] += bflo(v.z); av[i*8+5] += bfhi(v.z);
                    av[i*8+6] += bflo(v.w); av[i*8+7] += bfhi(v.w);
                }
            }
        }
        bar_only();    // previous strip's MFMA reads of At complete (no vm drain)
        {
            u16 tmp[32];
            #pragma unroll
            for (int i = 0; i < 32; ++i) tmp[i] = f2bf(av[i]);
            s16x8* dst = (s16x8*)&At[arow * LDP + kb];
            #pragma unroll
            for (int i = 0; i < 4; ++i) dst[i] = *(const s16x8*)&tmp[i * 8];
        }
        bar_lgkm();    // At visible (lgkm only)

        // ---- MFMA: 2 mtiles x 4 ntiles x 8 ktiles ----
        f32x4 acc[2][4];
        #pragma unroll
        for (int mt = 0; mt < 2; ++mt)
            #pragma unroll
            for (int nt = 0; nt < 4; ++nt) acc[mt][nt] = f32x4{0.f, 0.f, 0.f, 0.f};
        #pragma unroll
        for (int kt = 0; kt < 8; ++kt) {
            const int ko = kt * 32 + quad * 8;
            const s16x8 a0 = *(const s16x8*)&At[(n16) * LDP + ko];
            const s16x8 a1 = *(const s16x8*)&At[(16 + n16) * LDP + ko];
            #pragma unroll
            for (int nt = 0; nt < 4; ++nt) {
                acc[0][nt] = __builtin_amdgcn_mfma_f32_16x16x32_bf16(a0, bw[nt][kt], acc[0][nt], 0, 0, 0);
                acc[1][nt] = __builtin_amdgcn_mfma_f32_16x16x32_bf16(a1, bw[nt][kt], acc[1][nt], 0, 0, 0);
            }
        }

        // ---- epilogue: D row = quad*4+r (A-row), col = n16 (B-col) ----
        #pragma unroll
        for (int nt = 0; nt < 4; ++nt) {
            const int col = wv * 64 + nt * 16 + n16;
            const float bias = b1[col] + (b2 ? b2[col] : 0.0f);
            #pragma unroll
            for (int mt = 0; mt < 2; ++mt) {
                const int row0 = s * 32 + mt * 16 + quad * 4;
                #pragma unroll
                for (int r = 0; r < 4; ++r) {
                    const float v = acc[mt][nt][r] + bias;
                    const long idx = (long)(row0 + r) * 256 + col;
                    if (c_f32) ((float*)Cdst)[idx] = v;
                    else       ((u16*)Cdst)[idx]   = f2bf(v);
                }
            }
        }
    }
}

// ---------------------------------------------------------------------------
// P2 merged: 3 GEMMs (XX/XR/XU) in one launch, grid 1536 (matrix = bid>>9).
// A (bf16) staged with global_load_lds into LINEAR 16KB LDS; source addresses
// pre-swizzled with the involution  p ^= ((p>>9)&7)<<4  so the MFMA-side
// ds_read_b128 (same XOR applied) is bank-group-optimal.
// ---------------------------------------------------------------------------
__global__ __launch_bounds__(256, 2)
void gemm_p2(const u16* __restrict__ X,
             const float* __restrict__ W0, const float* __restrict__ W1, const float* __restrict__ W2,
             const float* __restrict__ bA0, const float* __restrict__ bA1, const float* __restrict__ bA2,
             const float* __restrict__ bB1, const float* __restrict__ bB2,
             u16* __restrict__ C0, u16* __restrict__ C1, u16* __restrict__ C2)
{
    __shared__ u16 At[32 * 256];     // 16 KiB, linear
    const int tid  = threadIdx.x;
    const int lane = tid & 63, wv = tid >> 6;
    const int quad = lane >> 4, n16 = lane & 15;

    const int m  = (int)blockIdx.x >> 9;      // which matrix 0..2
    const int s0 = (int)blockIdx.x & 511;
    const float* W  = (m == 0) ? W0 : ((m == 1) ? W1 : W2);
    const float* b1 = (m == 0) ? bA0 : ((m == 1) ? bA1 : bA2);
    const float* b2 = (m == 0) ? (const float*)nullptr : ((m == 1) ? bB1 : bB2);
    u16* C = (m == 0) ? C0 : ((m == 1) ? C1 : C2);

    // preload B fragments (same layout as gemm256)
    s16x8 bw[4][8];
    #pragma unroll
    for (int nt = 0; nt < 4; ++nt) {
        const int col = wv * 64 + nt * 16 + n16;
        #pragma unroll
        for (int kt = 0; kt < 8; ++kt) {
            const int kb0 = kt * 32 + quad * 8;
            s16x8 f;
            #pragma unroll
            for (int j = 0; j < 8; ++j) f[j] = (short)f2bf(W[(kb0 + j) * 256 + col]);
            bw[nt][kt] = f;
        }
    }

    // per-lane swizzled DMA source byte offsets (4 rounds of 1KB per wave)
    u32 myL[4];
    #pragma unroll
    for (int r = 0; r < 4; ++r) {
        const u32 p = ((u32)(wv * 4 + r) * 64 + (u32)lane) * 16;   // phys byte
        myL[r] = p ^ (((p >> 9) & 7u) << 4);                        // logical byte
    }
    const u32 key   = ((u32)(n16 & 7)) << 4;        // read-side XOR (bits 9-11 of row)
    const u32 base0 = (u32)n16 * 512 + (u32)quad * 16;
    const u32 base1 = base0 + 16 * 512;

    for (int s = s0; s < 2048; s += 512) {
        const char* src = (const char*)(X + (long)s * 32 * 256);
        bar_only();                               // prev strip's At reads done
        #pragma unroll
        for (int r = 0; r < 4; ++r)
            GLD_LDS16(src + myL[r], (char*)At + (u32)(wv * 4 + r) * 1024);
        asm volatile("s_waitcnt vmcnt(0)" ::: "memory");
        bar_only();                               // all waves' DMA landed

        f32x4 acc[2][4];
        #pragma unroll
        for (int mt = 0; mt < 2; ++mt)
            #pragma unroll
            for (int nt = 0; nt < 4; ++nt) acc[mt][nt] = f32x4{0.f, 0.f, 0.f, 0.f};
        #pragma unroll
        for (int kt = 0; kt < 8; ++kt) {
            const s16x8 a0 = *(const s16x8*)((const char*)At + (((base0 + (u32)kt * 64) ^ key)));
            const s16x8 a1 = *(const s16x8*)((const char*)At + (((base1 + (u32)kt * 64) ^ key)));
            #pragma unroll
            for (int nt = 0; nt < 4; ++nt) {
                acc[0][nt] = __builtin_amdgcn_mfma_f32_16x16x32_bf16(a0, bw[nt][kt], acc[0][nt], 0, 0, 0);
                acc[1][nt] = __builtin_amdgcn_mfma_f32_16x16x32_bf16(a1, bw[nt][kt], acc[1][nt], 0, 0, 0);
            }
        }

        #pragma unroll
        for (int nt = 0; nt < 4; ++nt) {
            const int col = wv * 64 + nt * 16 + n16;
            const float bias = b1[col] + (b2 ? b2[col] : 0.0f);
            #pragma unroll
            for (int mt = 0; mt < 2; ++mt) {
                const int row0 = s * 32 + mt * 16 + quad * 4;
                #pragma unroll
                for (int r = 0; r < 4; ++r) {
                    const float v = acc[mt][nt][r] + bias;
                    C[(long)(row0 + r) * 256 + col] = f2bf(v);
                }
            }
        }
    }
}

// ---------------------------------------------------------------------------
// Recurrence. 64 blocks x 512 threads. Block wg: dir = wg>>5, batches b0=(wg&31)*2.
// Wave w owns h-columns [w*32, w*32+32), both gates.
// MFMA: A = h fragment (row parity = seq), B = W cols. W-frags K-ROTATED:
// aw[g][nt][i] holds k-chunk (wave+i)&7, slot 0 = wave's OWN columns.
// Step tail: h16 -> shfl_xor pack -> 4 ds_bpermute (static addrs, independent
// of the hbuf ds_write) -> 4 slot-0 MFMAs PRE-barrier (zero-init carried acc).
// Post-barrier: 7 ds_reads + 28 MFMAs, select, elementwise.
// One lgkm-only barrier per step; Hg store + x prefetch stay in flight.
// ---------------------------------------------------------------------------
__global__ __launch_bounds__(512, 2)
void gru_rec(const u16* __restrict__ XX, const u16* __restrict__ XR, const u16* __restrict__ XU,
             const float* __restrict__ Wr, const float* __restrict__ Wu,
             u16* __restrict__ Hf, u16* __restrict__ Hb)
{
    __shared__ u16 hbuf[2][2 * LDPH];   // [buf][seq*LDPH + col]

    const int tid  = threadIdx.x;
    const int lane = tid & 63, wave = tid >> 6;
    const int quad = lane >> 4, n16 = lane & 15;
    const int wg  = blockIdx.x;
    const int dir = wg >> 5;             // 0 fwd, 1 bwd
    const int b0  = (wg & 31) * 2;       // two batches: b0, b0+1
    const int c0  = wave * 32;

    // ---- preload weight B-frags, K-rotated: slot i = chunk (wave+i)&7 ----
    s16x8 aw[2][2][8];
    #pragma unroll
    for (int g = 0; g < 2; ++g) {
        const float* Wg = g ? Wu : Wr;
        #pragma unroll
        for (int nt = 0; nt < 2; ++nt) {
            const int col = c0 + nt * 16 + n16;
            #pragma unroll
            for (int i = 0; i < 8; ++i) {
                const int kt  = (wave + i) & 7;
                const int kb0 = kt * 32 + quad * 8;
                s16x8 f;
                #pragma unroll
                for (int j = 0; j < 8; ++j) f[j] = (short)f2bf(Wg[(kb0 + j) * 256 + col]);
                aw[g][nt][i] = f;
            }
        }
    }

    // elementwise identity: one (seq, col) per lane
    const int  eseq = lane >> 5;                 // 0..1  (acc reg index)
    const int  ecl  = lane & 31;                 // 0..31
    const int  ntb  = ecl >> 4;                  // which n-tile holds this col
    const int  gcol = c0 + ecl;                  // global h column (ecl&15 == n16)
    const long xrow = (long)(b0 + eseq) * 1024;  // row base within [B*L]
    float hprev = 0.0f;

    // bpermute source-lane byte addrs for the slot-0 A-frag:
    // dst (quad,n16) word m <- packed pair from lane (n16&1)*32 + quad*8 + 2m
    const int bp0 = ((n16 & 1) * 32 + quad * 8) * 4;

    for (int i = tid; i < 2 * LDPH; i += 512) hbuf[0][i] = 0;   // h(0) = 0

    u16* const Hg = dir ? Hb : Hf;

    // x for step 0
    u16 cxx, cxr, cxu;
    {
        const long off = (xrow + (dir ? 1023 : 0)) * 256 + gcol;
        cxx = XX[off]; cxr = XR[off]; cxu = XU[off];
    }

    // carried accumulators: slot-0 (own chunk) contribution of the UPCOMING
    // step is already in them when stepbody begins. h(0)=0 -> start at 0.
    f32x4 a00 = f32x4{0.f,0.f,0.f,0.f}, a01 = a00, a10 = a00, a11 = a00;

    __syncthreads();

    auto stepbody = [&](int step, int pb) __attribute__((always_inline)) {
        const int t = dir ? 1023 - step : step;
        int sn = step + 1; if (sn > 1023) sn = 1023;
        const int tn = dir ? 1023 - sn : sn;

        // prefetch next step's x (full step of latency slack, counted vmcnt)
        const long offn = (xrow + tn) * 256 + gcol;
        const u16 nxx = XX[offn], nxr = XR[offn], nxu = XU[offn];

        // ---- matvec remainder: slots 1..7 from LDS ----
        const u16* hin = &hbuf[pb][0];
        #pragma unroll
        for (int i = 1; i < 8; ++i) {
            const int kt = (wave + i) & 7;
            const s16x8 hv = *(const s16x8*)(hin + (n16 & 1) * LDPH + kt * 32 + quad * 8);
            a00 = __builtin_amdgcn_mfma_f32_16x16x32_bf16(hv, aw[0][0][i], a00, 0, 0, 0);
            a01 = __builtin_amdgcn_mfma_f32_16x16x32_bf16(hv, aw[0][1][i], a01, 0, 0, 0);
            a10 = __builtin_amdgcn_mfma_f32_16x16x32_bf16(hv, aw[1][0][i], a10, 0, 0, 0);
            a11 = __builtin_amdgcn_mfma_f32_16x16x32_bf16(hv, aw[1][1][i], a11, 0, 0, 0);
        }

        // ---- in-lane select: this lane's (seq=eseq, col=gcol) pre-activations ----
        const float pr = ntb ? (eseq ? a01[1] : a01[0]) : (eseq ? a00[1] : a00[0]);
        const float pu = ntb ? (eseq ? a11[1] : a11[0]) : (eseq ? a10[1] : a10[0]);

        // ---- elementwise: exactly one (seq, col) per lane ----
        const float rr   = sigm(pr + bf2f(cxr));
        const float uu   = sigm(pu + bf2f(cxu));
        const float cand = tanhfast(rr * hprev + bf2f(cxx));
        hprev = cand + uu * (hprev - cand);
        const u16 h16 = f2bf(hprev);

        // ---- slot-0 A-frag from registers: pack lane pairs, 4 bpermutes ----
        const u32 me  = (u32)h16;
        const u32 oth = (u32)__shfl_xor((int)me, 1);
        const u32 P   = (lane & 1) ? (oth | (me << 16)) : (me | (oth << 16));
        const u32 w0 = (u32)__builtin_amdgcn_ds_bpermute(bp0,      (int)P);
        const u32 w1 = (u32)__builtin_amdgcn_ds_bpermute(bp0 + 8,  (int)P);
        const u32 w2 = (u32)__builtin_amdgcn_ds_bpermute(bp0 + 16, (int)P);
        const u32 w3 = (u32)__builtin_amdgcn_ds_bpermute(bp0 + 24, (int)P);

        hbuf[pb ^ 1][eseq * LDPH + gcol] = h16;       // next step's LDS operand (slots 1..7 of other waves)
        Hg[(xrow + t) * 256 + gcol]      = h16;       // persist for F-GEMM (fire & forget)

        // ---- pre-barrier slot-0 MFMAs: operands fully in-register ----
        {
            const s16x8 hv0 = __builtin_bit_cast(s16x8, (u32x4){w0, w1, w2, w3});
            f32x4 z = f32x4{0.f, 0.f, 0.f, 0.f};
            a00 = __builtin_amdgcn_mfma_f32_16x16x32_bf16(hv0, aw[0][0][0], z, 0, 0, 0);
            a01 = __builtin_amdgcn_mfma_f32_16x16x32_bf16(hv0, aw[0][1][0], z, 0, 0, 0);
            a10 = __builtin_amdgcn_mfma_f32_16x16x32_bf16(hv0, aw[1][0][0], z, 0, 0, 0);
            a11 = __builtin_amdgcn_mfma_f32_16x16x32_bf16(hv0, aw[1][1][0], z, 0, 0, 0);
        }

        cxx = nxx; cxr = nxr; cxu = nxu;
        bar_lgkm();                                   // hbuf[pb^1] visible; NO vmcnt drain
    };

    for (int sp = 0; sp < 512; ++sp) {
        stepbody(sp * 2,     0);
        stepbody(sp * 2 + 1, 1);
    }
}

// ---------------------------------------------------------------------------
extern "C" void kernel_launch(void* const* d_in, const int* in_sizes, int n_in,
                              void* d_out, int out_size, void* d_ws, size_t ws_size,
                              hipStream_t stream)
{
    const float* inputs = (const float*)d_in[0];
    const float* Wi_w = (const float*)d_in[1];
    const float* Wi_b = (const float*)d_in[2];
    const float* Wx_w = (const float*)d_in[3];
    const float* Wx_b = (const float*)d_in[4];
    const float* Ux_w = (const float*)d_in[5];
    const float* Ux_b = (const float*)d_in[6];
    const float* Rx_w = (const float*)d_in[7];
    const float* Rx_b = (const float*)d_in[8];
    const float* Wr_w = (const float*)d_in[9];
    const float* Wr_b = (const float*)d_in[10];
    const float* Wu_w = (const float*)d_in[11];
    const float* Wu_b = (const float*)d_in[12];
    const float* Wo_w = (const float*)d_in[13];
    const float* Wo_b = (const float*)d_in[14];

    const long E = 64L * 1024 * 256;
    u16* XX = (u16*)d_ws;
    u16* XR = XX + E;
    u16* XU = XR + E;
    u16* Hf = XU + E;      // also used as X (bf16) between P1 and P2 — dead before R writes it
    u16* Hb = Hf + E;
    u16* Xb = Hf;

    const int M = 64 * 1024;
    const dim3 gg(512), gb(256);

    // P1: X = inputs @ Wi + Wi_b
    hipLaunchKernelGGL(gemm256, gg, gb, 0, stream,
                       (const void*)inputs, 1, (const u16*)nullptr, Wi_w, Wi_b, (const float*)nullptr,
                       (void*)Xb, 0, M);
    // P2 (merged): XX = X@Wx + Wx_b ; XR = X@Ux + Ux_b + Wr_b ; XU = X@Rx + Rx_b + Wu_b
    hipLaunchKernelGGL(gemm_p2, dim3(1536), gb, 0, stream,
                       (const u16*)Xb,
                       Wx_w, Ux_w, Rx_w,
                       Wx_b, Ux_b, Rx_b,
                       Wr_b, Wu_b,
                       XX, XR, XU);
    // R: the sequential scan (both directions concurrently, 64 WGs)
    hipLaunchKernelGGL(gru_rec, dim3(64), dim3(512), 0, stream,
                       (const u16*)XX, (const u16*)XR, (const u16*)XU, Wr_w, Wu_w, Hf, Hb);
    // F: out = (Hf + Hb) @ Wo + Wo_b
    hipLaunchKernelGGL(gemm256, gg, gb, 0, stream,
                       (const void*)Hf, 0, (const u16*)Hb, Wo_w, Wo_b, (const float*)nullptr,
                       d_out, 1, M);
}

// Round 4
// 942.437 us; speedup vs baseline: 1.1345x; 1.1345x over previous
//
#include <hip/hip_runtime.h>

// ---------------------------------------------------------------------------
// GRU_13030930776564: bidirectional GRU, B=64, L=1024, DI=D=DO=256 (fp32 io).
//   P1: X  = bf16( inputs @ Wi + Wi_b )                        [65536 x 256]
//   P2: one merged kernel (grid 1536, matrix = bid>>9), A staged via
//       global_load_lds (16B) with XOR-swizzled source so linear LDS gives
//       conflict-free ds_read_b128:  phys = logical ^ (((logical>>9)&7)<<4.
//       XX = bf16( X @ Wx + Wx_b )
//       XR = bf16( X @ Ux + Ux_b + Wr_b )   (fold recurrent bias)
//       XU = bf16( X @ Rx + Rx_b + Wu_b )
//   R : 64 WGs x 512 thr; WG = 2 sequences (batch x dir). Weights-in-VGPR
//       MFMA, A = h (seq on M-row parity), B = W cols. Lane holds both seqs
//       of its own column in acc regs 0/1 (no LDS transpose).
//       R4: reverted R2/R3 pre-barrier experiments (both measured net-neg).
//       GATE-SPLIT schedule: 16 g=0 (r-gate) MFMAs first, then the
//       rr/cand trans chain overlaps the 16 g=1 (u-gate) MFMAs; only the
//       uu+blend+write tail is exposed after the last MFMA.
//       hbuf stride 288 (parities in disjoint bank-groups, 0 conflicts).
//       Per-step sync: s_barrier + lgkmcnt(0) only (no vmcnt drain) — the
//       Hg store and next-step x prefetch stay in flight across the barrier.
//   F : out = fp32( (Hf + Hb) @ Wo + Wo_b )
// ws layout (u16 elements, E = 64*1024*256): XX | XR | XU | Hf(=X) | Hb
// ---------------------------------------------------------------------------

typedef float   f32x4 __attribute__((ext_vector_type(4)));
typedef short   s16x8 __attribute__((ext_vector_type(8)));
typedef unsigned int u32;
typedef unsigned short u16;

#define LDP  264   // padded row stride for gemm256 At (u16 elems)
#define LDPH 288   // hbuf row stride: 288*2B = 576B = granule 36 ≡ 4 (mod 8)

__device__ __forceinline__ u16 f2bf(float x) {
    u32 u = __float_as_uint(x);
    return (u16)((u + 0x7FFFu + ((u >> 16) & 1u)) >> 16);   // RNE, inputs never NaN
}
__device__ __forceinline__ float bflo(u32 u) { return __uint_as_float(u << 16); }
__device__ __forceinline__ float bfhi(u32 u) { return __uint_as_float(u & 0xFFFF0000u); }
__device__ __forceinline__ float bf2f(u16 v) { return __uint_as_float((u32)v << 16); }

__device__ __forceinline__ float sigm(float z) {
    float e = __builtin_amdgcn_exp2f(z * -1.44269504f);
    return __builtin_amdgcn_rcpf(1.0f + e);
}
__device__ __forceinline__ float tanhfast(float y) {
    float e = __builtin_amdgcn_exp2f(y * 2.88539008f);     // e^(2y)
    return 1.0f - 2.0f * __builtin_amdgcn_rcpf(1.0f + e);  // handles +/-inf saturation
}

// Raw barrier helpers: compiler-level fences sandwich the hw barrier so LDS
// ops can't migrate across it, but NO vmcnt drain is forced.
__device__ __forceinline__ void bar_lgkm() {
    asm volatile("s_waitcnt lgkmcnt(0)" ::: "memory");
    __builtin_amdgcn_s_barrier();
    asm volatile("" ::: "memory");
}
__device__ __forceinline__ void bar_only() {
    asm volatile("" ::: "memory");
    __builtin_amdgcn_s_barrier();
    asm volatile("" ::: "memory");
}

#define GLD_LDS16(g, l) __builtin_amdgcn_global_load_lds( \
    (const __attribute__((address_space(1))) unsigned int*)(g), \
    (__attribute__((address_space(3))) unsigned int*)(l), 16, 0, 0)

// ---------------------------------------------------------------------------
// Generic K=256, N=256 GEMM (P1: f32 A in; F: bf16 A + A2 sum, f32 out).
// ---------------------------------------------------------------------------
__global__ __launch_bounds__(256, 2)
void gemm256(const void* __restrict__ Asrc, int a_f32, const u16* __restrict__ A2,
             const float* __restrict__ W, const float* __restrict__ b1,
             const float* __restrict__ b2, void* __restrict__ Cdst, int c_f32, int M)
{
    __shared__ u16 At[32 * LDP];
    const int tid  = threadIdx.x;
    const int lane = tid & 63, wv = tid >> 6;
    const int quad = lane >> 4, n16 = lane & 15;

    // preload B fragments: bw[nt][kt] holds W[k = kt*32+quad*8+j][col], col = wv*64+nt*16+n16
    s16x8 bw[4][8];
    #pragma unroll
    for (int nt = 0; nt < 4; ++nt) {
        const int col = wv * 64 + nt * 16 + n16;
        #pragma unroll
        for (int kt = 0; kt < 8; ++kt) {
            const int kb0 = kt * 32 + quad * 8;
            s16x8 f;
            #pragma unroll
            for (int j = 0; j < 8; ++j) f[j] = (short)f2bf(W[(kb0 + j) * 256 + col]);
            bw[nt][kt] = f;
        }
    }

    const int arow = tid >> 3, kb = (tid & 7) * 32;  // staging: 32 elements per thread
    float av[32];
    const int nstrip = M >> 5;

    for (int s = (int)blockIdx.x; s < nstrip; s += (int)gridDim.x) {
        // ---- load A strip (32 rows x 256) into regs ----
        const long base = (long)(s * 32 + arow) * 256 + kb;
        if (a_f32) {
            const float4* p = (const float4*)((const float*)Asrc + base);
            #pragma unroll
            for (int i = 0; i < 8; ++i) {
                float4 v = p[i];
                av[i*4+0] = v.x; av[i*4+1] = v.y; av[i*4+2] = v.z; av[i*4+3] = v.w;
            }
        } else {
            const uint4* p = (const uint4*)((const u16*)Asrc + base);
            #pragma unroll
            for (int i = 0; i < 4; ++i) {
                uint4 v = p[i];
                av[i*8+0] = bflo(v.x); av[i*8+1] = bfhi(v.x);
                av[i*8+2] = bflo(v.y); av[i*8+3] = bfhi(v.y);
                av[i*8+4] = bflo(v.z); av[i*8+5] = bfhi(v.z);
                av[i*8+6] = bflo(v.w); av[i*8+7] = bfhi(v.w);
            }
            if (A2) {
                const uint4* q = (const uint4*)(A2 + base);
                #pragma unroll
                for (int i = 0; i < 4; ++i) {
                    uint4 v = q[i];
                    av[i*8+0] += bflo(v.x); av[i*8+1] += bfhi(v.x);
                    av[i*8+2] += bflo(v.y); av[i*8+3] += bfhi(v.y);
                    av[i*8+4] += bflo(v.z); av[i*8+5] += bfhi(v.z);
                    av[i*8+6] += bflo(v.w); av[i*8+7] += bfhi(v.w);
                }
            }
        }
        bar_only();    // previous strip's MFMA reads of At complete (no vm drain)
        {
            u16 tmp[32];
            #pragma unroll
            for (int i = 0; i < 32; ++i) tmp[i] = f2bf(av[i]);
            s16x8* dst = (s16x8*)&At[arow * LDP + kb];
            #pragma unroll
            for (int i = 0; i < 4; ++i) dst[i] = *(const s16x8*)&tmp[i * 8];
        }
        bar_lgkm();    // At visible (lgkm only)

        // ---- MFMA: 2 mtiles x 4 ntiles x 8 ktiles ----
        f32x4 acc[2][4];
        #pragma unroll
        for (int mt = 0; mt < 2; ++mt)
            #pragma unroll
            for (int nt = 0; nt < 4; ++nt) acc[mt][nt] = f32x4{0.f, 0.f, 0.f, 0.f};
        #pragma unroll
        for (int kt = 0; kt < 8; ++kt) {
            const int ko = kt * 32 + quad * 8;
            const s16x8 a0 = *(const s16x8*)&At[(n16) * LDP + ko];
            const s16x8 a1 = *(const s16x8*)&At[(16 + n16) * LDP + ko];
            #pragma unroll
            for (int nt = 0; nt < 4; ++nt) {
                acc[0][nt] = __builtin_amdgcn_mfma_f32_16x16x32_bf16(a0, bw[nt][kt], acc[0][nt], 0, 0, 0);
                acc[1][nt] = __builtin_amdgcn_mfma_f32_16x16x32_bf16(a1, bw[nt][kt], acc[1][nt], 0, 0, 0);
            }
        }

        // ---- epilogue: D row = quad*4+r (A-row), col = n16 (B-col) ----
        #pragma unroll
        for (int nt = 0; nt < 4; ++nt) {
            const int col = wv * 64 + nt * 16 + n16;
            const float bias = b1[col] + (b2 ? b2[col] : 0.0f);
            #pragma unroll
            for (int mt = 0; mt < 2; ++mt) {
                const int row0 = s * 32 + mt * 16 + quad * 4;
                #pragma unroll
                for (int r = 0; r < 4; ++r) {
                    const float v = acc[mt][nt][r] + bias;
                    const long idx = (long)(row0 + r) * 256 + col;
                    if (c_f32) ((float*)Cdst)[idx] = v;
                    else       ((u16*)Cdst)[idx]   = f2bf(v);
                }
            }
        }
    }
}

// ---------------------------------------------------------------------------
// P2 merged: 3 GEMMs (XX/XR/XU) in one launch, grid 1536 (matrix = bid>>9).
// A (bf16) staged with global_load_lds into LINEAR 16KB LDS; source addresses
// pre-swizzled with the involution  p ^= ((p>>9)&7)<<4  so the MFMA-side
// ds_read_b128 (same XOR applied) is bank-group-optimal.
// ---------------------------------------------------------------------------
__global__ __launch_bounds__(256, 2)
void gemm_p2(const u16* __restrict__ X,
             const float* __restrict__ W0, const float* __restrict__ W1, const float* __restrict__ W2,
             const float* __restrict__ bA0, const float* __restrict__ bA1, const float* __restrict__ bA2,
             const float* __restrict__ bB1, const float* __restrict__ bB2,
             u16* __restrict__ C0, u16* __restrict__ C1, u16* __restrict__ C2)
{
    __shared__ u16 At[32 * 256];     // 16 KiB, linear
    const int tid  = threadIdx.x;
    const int lane = tid & 63, wv = tid >> 6;
    const int quad = lane >> 4, n16 = lane & 15;

    const int m  = (int)blockIdx.x >> 9;      // which matrix 0..2
    const int s0 = (int)blockIdx.x & 511;
    const float* W  = (m == 0) ? W0 : ((m == 1) ? W1 : W2);
    const float* b1 = (m == 0) ? bA0 : ((m == 1) ? bA1 : bA2);
    const float* b2 = (m == 0) ? (const float*)nullptr : ((m == 1) ? bB1 : bB2);
    u16* C = (m == 0) ? C0 : ((m == 1) ? C1 : C2);

    // preload B fragments (same layout as gemm256)
    s16x8 bw[4][8];
    #pragma unroll
    for (int nt = 0; nt < 4; ++nt) {
        const int col = wv * 64 + nt * 16 + n16;
        #pragma unroll
        for (int kt = 0; kt < 8; ++kt) {
            const int kb0 = kt * 32 + quad * 8;
            s16x8 f;
            #pragma unroll
            for (int j = 0; j < 8; ++j) f[j] = (short)f2bf(W[(kb0 + j) * 256 + col]);
            bw[nt][kt] = f;
        }
    }

    // per-lane swizzled DMA source byte offsets (4 rounds of 1KB per wave)
    u32 myL[4];
    #pragma unroll
    for (int r = 0; r < 4; ++r) {
        const u32 p = ((u32)(wv * 4 + r) * 64 + (u32)lane) * 16;   // phys byte
        myL[r] = p ^ (((p >> 9) & 7u) << 4);                        // logical byte
    }
    const u32 key   = ((u32)(n16 & 7)) << 4;        // read-side XOR (bits 9-11 of row)
    const u32 base0 = (u32)n16 * 512 + (u32)quad * 16;
    const u32 base1 = base0 + 16 * 512;

    for (int s = s0; s < 2048; s += 512) {
        const char* src = (const char*)(X + (long)s * 32 * 256);
        bar_only();                               // prev strip's At reads done
        #pragma unroll
        for (int r = 0; r < 4; ++r)
            GLD_LDS16(src + myL[r], (char*)At + (u32)(wv * 4 + r) * 1024);
        asm volatile("s_waitcnt vmcnt(0)" ::: "memory");
        bar_only();                               // all waves' DMA landed

        f32x4 acc[2][4];
        #pragma unroll
        for (int mt = 0; mt < 2; ++mt)
            #pragma unroll
            for (int nt = 0; nt < 4; ++nt) acc[mt][nt] = f32x4{0.f, 0.f, 0.f, 0.f};
        #pragma unroll
        for (int kt = 0; kt < 8; ++kt) {
            const s16x8 a0 = *(const s16x8*)((const char*)At + (((base0 + (u32)kt * 64) ^ key)));
            const s16x8 a1 = *(const s16x8*)((const char*)At + (((base1 + (u32)kt * 64) ^ key)));
            #pragma unroll
            for (int nt = 0; nt < 4; ++nt) {
                acc[0][nt] = __builtin_amdgcn_mfma_f32_16x16x32_bf16(a0, bw[nt][kt], acc[0][nt], 0, 0, 0);
                acc[1][nt] = __builtin_amdgcn_mfma_f32_16x16x32_bf16(a1, bw[nt][kt], acc[1][nt], 0, 0, 0);
            }
        }

        #pragma unroll
        for (int nt = 0; nt < 4; ++nt) {
            const int col = wv * 64 + nt * 16 + n16;
            const float bias = b1[col] + (b2 ? b2[col] : 0.0f);
            #pragma unroll
            for (int mt = 0; mt < 2; ++mt) {
                const int row0 = s * 32 + mt * 16 + quad * 4;
                #pragma unroll
                for (int r = 0; r < 4; ++r) {
                    const float v = acc[mt][nt][r] + bias;
                    C[(long)(row0 + r) * 256 + col] = f2bf(v);
                }
            }
        }
    }
}

// ---------------------------------------------------------------------------
// Recurrence. 64 blocks x 512 threads. Block wg: dir = wg>>5, batches b0=(wg&31)*2.
// Wave w owns h-columns [w*32, w*32+32), both gates.
// MFMA: A = h fragment (row parity = seq), B = W cols aw[g][nt][kt].
// GATE-SPLIT schedule per step:
//   16 g=0 MFMAs -> select pr -> rr=sigm, cand=tanh (overlaps:) 16 g=1 MFMAs
//   -> select pu -> uu=sigm -> blend -> h16 -> ds_write + global store.
// Only the uu/blend/write tail is exposed after the last MFMA.
// One lgkm-only barrier per step; Hg store + x prefetch stay in flight.
// ---------------------------------------------------------------------------
__global__ __launch_bounds__(512, 2)
void gru_rec(const u16* __restrict__ XX, const u16* __restrict__ XR, const u16* __restrict__ XU,
             const float* __restrict__ Wr, const float* __restrict__ Wu,
             u16* __restrict__ Hf, u16* __restrict__ Hb)
{
    __shared__ u16 hbuf[2][2 * LDPH];   // [buf][seq*LDPH + col]

    const int tid  = threadIdx.x;
    const int lane = tid & 63, wave = tid >> 6;
    const int quad = lane >> 4, n16 = lane & 15;
    const int wg  = blockIdx.x;
    const int dir = wg >> 5;             // 0 fwd, 1 bwd
    const int b0  = (wg & 31) * 2;       // two batches: b0, b0+1
    const int c0  = wave * 32;

    // ---- preload weight B-frags: aw[g][nt][kt], B[k][n=col] = W_g[k][col] ----
    s16x8 aw[2][2][8];
    #pragma unroll
    for (int g = 0; g < 2; ++g) {
        const float* Wg = g ? Wu : Wr;
        #pragma unroll
        for (int nt = 0; nt < 2; ++nt) {
            const int col = c0 + nt * 16 + n16;
            #pragma unroll
            for (int kt = 0; kt < 8; ++kt) {
                const int kb0 = kt * 32 + quad * 8;
                s16x8 f;
                #pragma unroll
                for (int j = 0; j < 8; ++j) f[j] = (short)f2bf(Wg[(kb0 + j) * 256 + col]);
                aw[g][nt][kt] = f;
            }
        }
    }

    // elementwise identity: one (seq, col) per lane
    const int  eseq = lane >> 5;                 // 0..1  (acc reg index)
    const int  ecl  = lane & 31;                 // 0..31
    const int  ntb  = ecl >> 4;                  // which n-tile holds this col
    const int  gcol = c0 + ecl;                  // global h column (ecl&15 == n16)
    const long xrow = (long)(b0 + eseq) * 1024;  // row base within [B*L]
    float hprev = 0.0f;

    for (int i = tid; i < 2 * LDPH; i += 512) hbuf[0][i] = 0;   // h(0) = 0

    u16* const Hg = dir ? Hb : Hf;

    // x for step 0
    u16 cxx, cxr, cxu;
    {
        const long off = (xrow + (dir ? 1023 : 0)) * 256 + gcol;
        cxx = XX[off]; cxr = XR[off]; cxu = XU[off];
    }
    __syncthreads();

    auto stepbody = [&](int step, int pb) __attribute__((always_inline)) {
        const int t = dir ? 1023 - step : step;
        int sn = step + 1; if (sn > 1023) sn = 1023;
        const int tn = dir ? 1023 - sn : sn;

        // prefetch next step's x (full step of latency slack, counted vmcnt)
        const long offn = (xrow + tn) * 256 + gcol;
        const u16 nxx = XX[offn], nxr = XR[offn], nxu = XU[offn];

        const u16* hrow = &hbuf[pb][0] + (n16 & 1) * LDPH;

        // ---- gate r (g=0): 8 ds_reads + 16 MFMAs ----
        f32x4 a00 = f32x4{0.f,0.f,0.f,0.f}, a01 = a00;
        #pragma unroll
        for (int kt = 0; kt < 8; ++kt) {
            const s16x8 hv = *(const s16x8*)(hrow + kt * 32 + quad * 8);
            a00 = __builtin_amdgcn_mfma_f32_16x16x32_bf16(hv, aw[0][0][kt], a00, 0, 0, 0);
            a01 = __builtin_amdgcn_mfma_f32_16x16x32_bf16(hv, aw[0][1][kt], a01, 0, 0, 0);
        }
        // r-chain: depends only on g=0 accs -> overlaps the g=1 MFMA pipe below
        const float pr   = ntb ? (eseq ? a01[1] : a01[0]) : (eseq ? a00[1] : a00[0]);
        const float rr   = sigm(pr + bf2f(cxr));
        const float cand = tanhfast(rr * hprev + bf2f(cxx));

        // ---- gate u (g=1): 8 ds_reads + 16 MFMAs ----
        f32x4 a10 = f32x4{0.f,0.f,0.f,0.f}, a11 = a10;
        #pragma unroll
        for (int kt = 0; kt < 8; ++kt) {
            const s16x8 hv = *(const s16x8*)(hrow + kt * 32 + quad * 8);
            a10 = __builtin_amdgcn_mfma_f32_16x16x32_bf16(hv, aw[1][0][kt], a10, 0, 0, 0);
            a11 = __builtin_amdgcn_mfma_f32_16x16x32_bf16(hv, aw[1][1][kt], a11, 0, 0, 0);
        }
        const float pu = ntb ? (eseq ? a11[1] : a11[0]) : (eseq ? a10[1] : a10[0]);
        const float uu = sigm(pu + bf2f(cxu));
        hprev = cand + uu * (hprev - cand);
        const u16 h16 = f2bf(hprev);

        hbuf[pb ^ 1][eseq * LDPH + gcol] = h16;       // next step's A-operand
        Hg[(xrow + t) * 256 + gcol]      = h16;       // persist for F-GEMM (fire & forget)

        cxx = nxx; cxr = nxr; cxu = nxu;
        bar_lgkm();                                   // hbuf[pb^1] visible; NO vmcnt drain
    };

    for (int sp = 0; sp < 512; ++sp) {
        stepbody(sp * 2,     0);
        stepbody(sp * 2 + 1, 1);
    }
}

// ---------------------------------------------------------------------------
extern "C" void kernel_launch(void* const* d_in, const int* in_sizes, int n_in,
                              void* d_out, int out_size, void* d_ws, size_t ws_size,
                              hipStream_t stream)
{
    const float* inputs = (const float*)d_in[0];
    const float* Wi_w = (const float*)d_in[1];
    const float* Wi_b = (const float*)d_in[2];
    const float* Wx_w = (const float*)d_in[3];
    const float* Wx_b = (const float*)d_in[4];
    const float* Ux_w = (const float*)d_in[5];
    const float* Ux_b = (const float*)d_in[6];
    const float* Rx_w = (const float*)d_in[7];
    const float* Rx_b = (const float*)d_in[8];
    const float* Wr_w = (const float*)d_in[9];
    const float* Wr_b = (const float*)d_in[10];
    const float* Wu_w = (const float*)d_in[11];
    const float* Wu_b = (const float*)d_in[12];
    const float* Wo_w = (const float*)d_in[13];
    const float* Wo_b = (const float*)d_in[14];

    const long E = 64L * 1024 * 256;
    u16* XX = (u16*)d_ws;
    u16* XR = XX + E;
    u16* XU = XR + E;
    u16* Hf = XU + E;      // also used as X (bf16) between P1 and P2 — dead before R writes it
    u16* Hb = Hf + E;
    u16* Xb = Hf;

    const int M = 64 * 1024;
    const dim3 gg(512), gb(256);

    // P1: X = inputs @ Wi + Wi_b
    hipLaunchKernelGGL(gemm256, gg, gb, 0, stream,
                       (const void*)inputs, 1, (const u16*)nullptr, Wi_w, Wi_b, (const float*)nullptr,
                       (void*)Xb, 0, M);
    // P2 (merged): XX = X@Wx + Wx_b ; XR = X@Ux + Ux_b + Wr_b ; XU = X@Rx + Rx_b + Wu_b
    hipLaunchKernelGGL(gemm_p2, dim3(1536), gb, 0, stream,
                       (const u16*)Xb,
                       Wx_w, Ux_w, Rx_w,
                       Wx_b, Ux_b, Rx_b,
                       Wr_b, Wu_b,
                       XX, XR, XU);
    // R: the sequential scan (both directions concurrently, 64 WGs)
    hipLaunchKernelGGL(gru_rec, dim3(64), dim3(512), 0, stream,
                       (const u16*)XX, (const u16*)XR, (const u16*)XU, Wr_w, Wu_w, Hf, Hb);
    // F: out = (Hf + Hb) @ Wo + Wo_b
    hipLaunchKernelGGL(gemm256, gg, gb, 0, stream,
                       (const void*)Hf, 0, (const u16*)Hb, Wo_w, Wo_b, (const float*)nullptr,
                       d_out, 1, M);
}